// Round 1
// baseline (1020.436 us; speedup 1.0000x reference)
//
#include <hip/hip_runtime.h>
#include <math.h>

// Problem constants
#define NTOT 16384        // N = B*T
#define GG 2
#define MM 1024
#define DD 256
// Kernel tiling
#define BLOCK_ROWS 16     // rows per block
#define RPW 2             // rows per wave
#define NTHREADS 512      // 8 waves
#define DCH 32            // d-chunk per stage
#define EPITCH 260        // 256 + 4 pad (keeps 16B alignment, breaks write conflicts)

// Output layout (flat float32)
#define OFF_Q  ((size_t)0)
#define OFF_CP ((size_t)8388608)
#define OFF_PP ((size_t)8388610)
#define OFF_I  ((size_t)8388612)
#define OFF_L  ((size_t)8421380)

__device__ inline float wave_sum_f(float v) {
#pragma unroll
  for (int o = 32; o > 0; o >>= 1) v += __shfl_xor(v, o);
  return v;
}
__device__ inline double wave_sum_d(double v) {
#pragma unroll
  for (int o = 32; o > 0; o >>= 1) v += __shfl_xor(v, o);
  return v;
}

// ---- kernel 0: zero accumulators, precompute sq_e = sum(e^2) per (g,m) ----
__global__ void vq_init(const float* __restrict__ emb, float* __restrict__ sq_e,
                        float* __restrict__ avg, int* __restrict__ hist,
                        double* __restrict__ loss) {
  int gid = blockIdx.x * 256 + threadIdx.x;
  if (gid < GG * MM) {
    const float* er = emb + (size_t)gid * DD;
    float s = 0.f;
    for (int d = 0; d < DD; d += 4) {
      float4 v = *(const float4*)&er[d];
      s += v.x * v.x + v.y * v.y + v.z * v.z + v.w * v.w;
    }
    sq_e[gid] = s;
    avg[gid] = 0.f;
    hist[gid] = 0;
    if (gid == 0) *loss = 0.0;
  }
}

// ---- kernel 1: fused distances + softmax stats + gumbel argmax + outputs ----
__global__ __launch_bounds__(NTHREADS) void vq_main(
    const float* __restrict__ x, const float* __restrict__ emb,
    const float* __restrict__ gum, const float* __restrict__ sq_e,
    float* __restrict__ out, float* __restrict__ avg,
    int* __restrict__ hist, double* __restrict__ loss) {
  __shared__ float e_t[DCH][EPITCH];      // e tile, transposed [d][m]
  __shared__ float x_t[BLOCK_ROWS][DD];   // x rows
  __shared__ float colsum[MM];            // per-block avg_probs partial
  __shared__ float sqe_s[MM];

  const int g = blockIdx.y;
  const int n0 = blockIdx.x * BLOCK_ROWS;
  const int t = threadIdx.x;
  const int wave = t >> 6, lane = t & 63;
  const float* eg = emb + (size_t)g * MM * DD;

  // stage x rows (coalesced float4)
#pragma unroll
  for (int p = 0; p < 2; ++p) {
    int idx = p * NTHREADS + t;
    int row = idx >> 6, f4 = idx & 63;
    *(float4*)&x_t[row][f4 * 4] =
        *(const float4*)&x[(size_t)(n0 + row) * (GG * DD) + (size_t)g * DD + f4 * 4];
  }
  for (int i = t; i < MM; i += NTHREADS) {
    colsum[i] = 0.f;
    sqe_s[i] = sq_e[g * MM + i];
  }
  // (first __syncthreads inside the dc loop covers these stores)

  // per-lane state; lane owns m = mg*256 + 4*lane + q
  float Z[RPW] = {0.f, 0.f};
  float hval[RPW] = {-INFINITY, -INFINITY};
  int   hidx[RPW] = {0, 0};
  float z1[RPW] = {-INFINITY, -INFINITY}, z2[RPW] = {-INFINITY, -INFINITY};
  int   zi1[RPW] = {0, 0}, zi2[RPW] = {0, 0};
  float estore[RPW][16];

#pragma unroll
  for (int mg = 0; mg < 4; ++mg) {
    float acc[RPW][4] = {{0.f, 0.f, 0.f, 0.f}, {0.f, 0.f, 0.f, 0.f}};
#pragma unroll 1
    for (int dc = 0; dc < DD / DCH; ++dc) {
      __syncthreads();
      // stage e[mg*256 .. +255][dc*32 .. +31] transposed into e_t[d][m]
#pragma unroll
      for (int p = 0; p < 4; ++p) {
        int idx = p * NTHREADS + t;
        int ml = idx >> 3, d4 = (idx & 7) * 4;
        float4 v = *(const float4*)&eg[(size_t)(mg * 256 + ml) * DD + dc * DCH + d4];
        e_t[d4 + 0][ml] = v.x;
        e_t[d4 + 1][ml] = v.y;
        e_t[d4 + 2][ml] = v.z;
        e_t[d4 + 3][ml] = v.w;
      }
      __syncthreads();
#pragma unroll
      for (int d = 0; d < DCH; ++d) {
        float4 e4 = *(const float4*)&e_t[d][lane * 4];  // ds_read_b128, conflict-free
#pragma unroll
        for (int r = 0; r < RPW; ++r) {
          float xv = x_t[wave * RPW + r][dc * DCH + d];  // broadcast
          acc[r][0] = fmaf(xv, e4.x, acc[r][0]);
          acc[r][1] = fmaf(xv, e4.y, acc[r][1]);
          acc[r][2] = fmaf(xv, e4.z, acc[r][2]);
          acc[r][3] = fmaf(xv, e4.w, acc[r][3]);
        }
      }
    }
    // m-group epilogue: logits (shifted by +sq_x, row-constant), exp, argmax tracking
    float4 sq4 = *(const float4*)&sqe_s[mg * 256 + lane * 4];
    const float sqv[4] = {sq4.x, sq4.y, sq4.z, sq4.w};
#pragma unroll
    for (int r = 0; r < RPW; ++r) {
      int n = n0 + wave * RPW + r;
      float4 u4 = *(const float4*)&gum[(size_t)n * (GG * MM) + (size_t)g * MM + mg * 256 + lane * 4];
      const float uu[4] = {u4.x, u4.y, u4.z, u4.w};
#pragma unroll
      for (int q = 0; q < 4; ++q) {
        int m = mg * 256 + lane * 4 + q;
        float lp = 2.f * acc[r][q] - sqv[q];   // logits + ||x||^2 (shift-invariant uses only)
        float ev = expf(lp);
        Z[r] += ev;
        estore[r][mg * 4 + q] = ev;
        if (lp > hval[r]) { hval[r] = lp; hidx[r] = m; }
        float gmb = -logf(-logf(uu[q]));
        float z = lp + gmb;
        if (z > z1[r]) { z2[r] = z1[r]; zi2[r] = zi1[r]; z1[r] = z; zi1[r] = m; }
        else if (z > z2[r]) { z2[r] = z; zi2[r] = m; }
      }
    }
  }

  // per-row wave reductions + outputs
#pragma unroll
  for (int r = 0; r < RPW; ++r) {
    const int row = wave * RPW + r;
    const int n = n0 + row;
    float Zr = wave_sum_f(Z[r]);
    // hard argmax merge (ties -> smaller index, matching jnp.argmax)
    float hv = hval[r]; int hi = hidx[r];
#pragma unroll
    for (int o = 32; o > 0; o >>= 1) {
      float ov = __shfl_xor(hv, o); int oi = __shfl_xor(hi, o);
      if (ov > hv || (ov == hv && oi < hi)) { hv = ov; hi = oi; }
    }
    // gumbel top-2 merge
    float v1 = z1[r], v2 = z2[r]; int i1 = zi1[r], i2 = zi2[r];
#pragma unroll
    for (int o = 32; o > 0; o >>= 1) {
      float w1 = __shfl_xor(v1, o), w2 = __shfl_xor(v2, o);
      int j1 = __shfl_xor(i1, o), j2 = __shfl_xor(i2, o);
      if (w1 > v1 || (w1 == v1 && j1 < i1)) {
        float nv2; int ni2;
        if (v1 > w2 || (v1 == w2 && i1 < j2)) { nv2 = v1; ni2 = i1; }
        else { nv2 = w2; ni2 = j2; }
        v1 = w1; i1 = j1; v2 = nv2; i2 = ni2;
      } else if (w1 > v2 || (w1 == v2 && j1 < i2)) {
        v2 = w1; i2 = j1;
      }
    }
    int fidx = i1;
    if (v1 - v2 < 1e-2f) {
      // fp64 refinement of the two candidates (wave-parallel over d)
      const float* erA = eg + (size_t)i1 * DD;
      const float* erB = eg + (size_t)i2 * DD;
      double dA = 0, sA = 0, dB = 0, sB = 0;
#pragma unroll
      for (int k = 0; k < 4; ++k) {
        int d = lane * 4 + k;
        double xv = (double)x_t[row][d];
        double ea = (double)erA[d], eb = (double)erB[d];
        dA += xv * ea; sA += ea * ea;
        dB += xv * eb; sB += eb * eb;
      }
      dA = wave_sum_d(dA); sA = wave_sum_d(sA);
      dB = wave_sum_d(dB); sB = wave_sum_d(sB);
      double uA = (double)gum[(size_t)n * (GG * MM) + (size_t)g * MM + i1];
      double uB = (double)gum[(size_t)n * (GG * MM) + (size_t)g * MM + i2];
      double zA = 2.0 * dA - sA - log(-log(uA));
      double zB = 2.0 * dB - sB - log(-log(uB));
      if (zB > zA || (zB == zA && i2 < i1)) fidx = i2;
    }
    if (lane == 0) {
      out[OFF_I + (size_t)n * GG + g] = (float)fidx;
      atomicAdd(&hist[g * MM + hi], 1);
    }
    // quantized row = embedding[g, fidx, :]; commitment-loss partial
    const float* er = eg + (size_t)fidx * DD;
    float4 ev4 = *(const float4*)&er[lane * 4];
    float4 xv4 = *(const float4*)&x_t[row][lane * 4];
    *(float4*)&out[OFF_Q + (size_t)n * (GG * DD) + (size_t)g * DD + lane * 4] = ev4;
    float dx = xv4.x - ev4.x, dy = xv4.y - ev4.y, dz = xv4.z - ev4.z, dw = xv4.w - ev4.w;
    float ds = wave_sum_f(dx * dx + dy * dy + dz * dz + dw * dw);
    if (lane == 0) atomicAdd(loss, (double)ds);
    // avg_probs partial: p = exp / Z
    float invZ = 1.f / Zr;
#pragma unroll
    for (int mg = 0; mg < 4; ++mg)
#pragma unroll
      for (int q = 0; q < 4; ++q)
        atomicAdd(&colsum[mg * 256 + lane * 4 + q], estore[r][mg * 4 + q] * invZ);
  }
  __syncthreads();
  for (int i = t; i < MM; i += NTHREADS)
    atomicAdd(&avg[g * MM + i], colsum[i]);
}

// ---- kernel 2: entropies + loss finalize ----
__global__ void vq_fin(const float* __restrict__ avg, const int* __restrict__ hist,
                       const double* __restrict__ loss, float* __restrict__ out) {
  int g = blockIdx.x, t = threadIdx.x;
  float cp = 0.f, pp = 0.f;
  for (int m = t; m < MM; m += 256) {
    float hp = (float)hist[g * MM + m] * (1.f / 16384.f);
    cp += hp * log2f(hp + 1e-10f);
    float ap = avg[g * MM + m] * (1.f / 16384.f);
    pp += ap * log2f(ap + 1e-10f);
  }
  cp = wave_sum_f(cp);
  pp = wave_sum_f(pp);
  __shared__ float sc[4], sp[4];
  int wave = t >> 6, lane = t & 63;
  if (lane == 0) { sc[wave] = cp; sp[wave] = pp; }
  __syncthreads();
  if (t == 0) {
    out[OFF_CP + g] = -(sc[0] + sc[1] + sc[2] + sc[3]);
    out[OFF_PP + g] = -(sp[0] + sp[1] + sp[2] + sp[3]);
    if (g == 0) out[OFF_L] = (float)(*loss * (1.0 / 8388608.0));
  }
}

extern "C" void kernel_launch(void* const* d_in, const int* in_sizes, int n_in,
                              void* d_out, int out_size, void* d_ws, size_t ws_size,
                              hipStream_t stream) {
  const float* x = (const float*)d_in[0];
  const float* emb = (const float*)d_in[1];
  const float* gum = (const float*)d_in[2];
  float* out = (float*)d_out;
  // workspace layout: sq_e[2048] f32 | avg[2048] f32 | hist[2048] i32 | loss f64
  float* sq_e = (float*)d_ws;
  float* avg = sq_e + 2048;
  int* hist = (int*)(avg + 2048);
  double* loss = (double*)((char*)d_ws + 24576);

  vq_init<<<8, 256, 0, stream>>>(emb, sq_e, avg, hist, loss);
  vq_main<<<dim3(NTOT / BLOCK_ROWS, GG), NTHREADS, 0, stream>>>(
      x, emb, gum, sq_e, out, avg, hist, loss);
  vq_fin<<<GG, 256, 0, stream>>>(avg, hist, loss, out);
}

// Round 2
// 531.093 us; speedup vs baseline: 1.9214x; 1.9214x over previous
//
#include <hip/hip_runtime.h>
#include <math.h>

// Problem constants
#define NTOT 16384        // N = B*T
#define GG 2
#define MM 1024
#define DD 256

// Output layout (flat float32)
#define OFF_Q  ((size_t)0)
#define OFF_CP ((size_t)8388608)
#define OFF_PP ((size_t)8388610)
#define OFF_I  ((size_t)8388612)
#define OFF_L  ((size_t)8421380)

#define SHIFT 40.0f       // row-constant logit shift: moves exp() into safe range
#define REFINE_GAP 0.03f  // fp64 re-check threshold (split-bf16 logit err <= ~5e-3)

typedef __attribute__((ext_vector_type(8))) short bf16x8;
typedef __attribute__((ext_vector_type(4))) float f32x4;

__device__ inline float wave_sum_f(float v) {
#pragma unroll
  for (int o = 32; o > 0; o >>= 1) v += __shfl_xor(v, o);
  return v;
}

__device__ inline unsigned short f2bf(float f) {
  unsigned u = __float_as_uint(f);
  return (unsigned short)((u + 0x7fffu + ((u >> 16) & 1u)) >> 16);
}
__device__ inline float bf2f(unsigned short h) {
  return __uint_as_float(((unsigned)h) << 16);
}

// ---- kernel 0: sq_e, bf16 hi/lo split of embedding, zero accumulators ----
__global__ void vq_init2(const float* __restrict__ emb, float* __restrict__ sq_e,
                         float* __restrict__ avg, int* __restrict__ hist,
                         double* __restrict__ loss, unsigned short* __restrict__ eh,
                         unsigned short* __restrict__ el, int do_split) {
  const int row = blockIdx.x * 4 + (threadIdx.x >> 6);   // 512 blocks x 4 rows
  const int lane = threadIdx.x & 63;
  float4 e4 = *(const float4*)&emb[(size_t)row * DD + lane * 4];
  float s = e4.x * e4.x + e4.y * e4.y + e4.z * e4.z + e4.w * e4.w;
  s = wave_sum_f(s);
  if (do_split) {
    ushort4 h, l;
    h.x = f2bf(e4.x); l.x = f2bf(e4.x - bf2f(h.x));
    h.y = f2bf(e4.y); l.y = f2bf(e4.y - bf2f(h.y));
    h.z = f2bf(e4.z); l.z = f2bf(e4.z - bf2f(h.z));
    h.w = f2bf(e4.w); l.w = f2bf(e4.w - bf2f(h.w));
    *(ushort4*)&eh[(size_t)row * DD + lane * 4] = h;
    *(ushort4*)&el[(size_t)row * DD + lane * 4] = l;
  }
  if (lane == 0) sq_e[row] = s;
  if (blockIdx.x == 0) {
    for (int i = threadIdx.x; i < GG * MM; i += 256) { avg[i] = 0.f; hist[i] = 0; }
    if (threadIdx.x == 0) *loss = 0.0;
  }
}

// ---- fast main: split-bf16 MFMA, 16 rows/block, m split across 4 waves ----
__global__ __launch_bounds__(256, 3) void vq_main_fast(
    const float* __restrict__ x, const float* __restrict__ emb,
    const float* __restrict__ gum, const float* __restrict__ sq_e,
    const unsigned short* __restrict__ eh, const unsigned short* __restrict__ el,
    float* __restrict__ out, float* __restrict__ avg,
    int* __restrict__ hist, double* __restrict__ loss) {
  __shared__ unsigned short est_lds[4][16][264];  // exps (bf16), padded pitch
  __shared__ float colsum[MM];
  __shared__ float red[16][4][8];
  __shared__ float fin_invZ[16];
  __shared__ int fin_idx[16];

  const int g = blockIdx.y;
  const int n0 = blockIdx.x * 16;
  const int t = threadIdx.x;
  const int wave = t >> 6, lane = t & 63;
  const int quad = lane >> 4, l15 = lane & 15;
  const int wm0 = wave * 256;  // this wave's m base (256 cols = 16 tiles)

  for (int i = t; i < MM; i += 256) colsum[i] = 0.f;

  // A strip: 16 rows x 256 k as split-bf16 MFMA frags, resident in VGPRs.
  // A-frag layout: lane holds A[m=lane&15][k=quad*8+j]
  bf16x8 ah[8], al[8];
  {
    const float* xr = x + (size_t)(n0 + l15) * (GG * DD) + (size_t)g * DD + quad * 8;
#pragma unroll
    for (int ks = 0; ks < 8; ++ks) {
      float4 fa = *(const float4*)(xr + ks * 32);
      float4 fb = *(const float4*)(xr + ks * 32 + 4);
      float f[8] = {fa.x, fa.y, fa.z, fa.w, fb.x, fb.y, fb.z, fb.w};
#pragma unroll
      for (int j = 0; j < 8; ++j) {
        unsigned short h = f2bf(f[j]);
        ah[ks][j] = (short)h;
        al[ks][j] = (short)f2bf(f[j] - bf2f(h));
      }
    }
  }

  const unsigned short* ehb = eh + ((size_t)g * MM + wm0 + l15) * DD + quad * 8;
  const unsigned short* elb = el + ((size_t)g * MM + wm0 + l15) * DD + quad * 8;
  const float* sqb = sq_e + g * MM + wm0 + l15;

  float Z[4] = {0.f, 0.f, 0.f, 0.f};
  float hv[4] = {-INFINITY, -INFINITY, -INFINITY, -INFINITY};
  int hid[4] = {0, 0, 0, 0};
  float z1[4] = {-INFINITY, -INFINITY, -INFINITY, -INFINITY};
  float z2[4] = {-INFINITY, -INFINITY, -INFINITY, -INFINITY};
  int i1[4] = {0, 0, 0, 0}, i2[4] = {0, 0, 0, 0};

#pragma unroll 2
  for (int tt = 0; tt < 16; ++tt) {
    // prefetch epilogue operands before the MFMA burst
    float sqv = sqb[tt * 16];
    float gv[4];
#pragma unroll
    for (int r = 0; r < 4; ++r)
      gv[r] = gum[((size_t)(n0 + quad * 4 + r) * GG + g) * MM + wm0 + tt * 16 + l15];

    f32x4 a0 = {0.f, 0.f, 0.f, 0.f}, a1 = {0.f, 0.f, 0.f, 0.f}, a2 = {0.f, 0.f, 0.f, 0.f};
#pragma unroll
    for (int ks = 0; ks < 8; ++ks) {
      bf16x8 bh = *(const bf16x8*)(ehb + (size_t)tt * 16 * DD + ks * 32);
      bf16x8 bl = *(const bf16x8*)(elb + (size_t)tt * 16 * DD + ks * 32);
      a0 = __builtin_amdgcn_mfma_f32_16x16x32_bf16(ah[ks], bh, a0, 0, 0, 0);
      a1 = __builtin_amdgcn_mfma_f32_16x16x32_bf16(ah[ks], bl, a1, 0, 0, 0);
      a2 = __builtin_amdgcn_mfma_f32_16x16x32_bf16(al[ks], bh, a2, 0, 0, 0);
    }
    const int colL = tt * 16 + l15;
    const int colG = wm0 + colL;
#pragma unroll
    for (int r = 0; r < 4; ++r) {
      // C/D layout: col=lane&15, row=quad*4+reg
      float lp = 2.f * (a0[r] + a1[r] + a2[r]) - sqv + SHIFT;
      float ev = expf(fminf(lp, 80.f));
      Z[r] += ev;
      est_lds[wave][quad * 4 + r][colL] = f2bf(ev);
      if (lp > hv[r]) { hv[r] = lp; hid[r] = colG; }
      float zz = lp - logf(-logf(gv[r]));
      if (zz > z1[r]) { z2[r] = z1[r]; i2[r] = i1[r]; z1[r] = zz; i1[r] = colG; }
      else if (zz > z2[r]) { z2[r] = zz; i2[r] = colG; }
    }
  }

  // per-row reduction across the 16 lanes of each quad (rows quad*4+r)
#pragma unroll
  for (int r = 0; r < 4; ++r) {
    float Zr = Z[r], hvr = hv[r];
    int hir = hid[r];
    float v1 = z1[r], v2 = z2[r];
    int j1 = i1[r], j2 = i2[r];
#pragma unroll
    for (int o = 1; o <= 8; o <<= 1) {
      Zr += __shfl_xor(Zr, o);
      float ohv = __shfl_xor(hvr, o); int ohi = __shfl_xor(hir, o);
      if (ohv > hvr || (ohv == hvr && ohi < hir)) { hvr = ohv; hir = ohi; }
      float w1 = __shfl_xor(v1, o), w2 = __shfl_xor(v2, o);
      int k1 = __shfl_xor(j1, o), k2 = __shfl_xor(j2, o);
      if (w1 > v1 || (w1 == v1 && k1 < j1)) {
        if (v1 > w2 || (v1 == w2 && j1 < k2)) { v2 = v1; j2 = j1; }
        else { v2 = w2; j2 = k2; }
        v1 = w1; j1 = k1;
      } else if (w1 > v2 || (w1 == v2 && k1 < j2)) { v2 = w1; j2 = k1; }
    }
    if (l15 == 0) {
      float* rp = red[quad * 4 + r][wave];
      rp[0] = Zr; rp[1] = hvr; rp[2] = __int_as_float(hir);
      rp[3] = v1; rp[4] = __int_as_float(j1);
      rp[5] = v2; rp[6] = __int_as_float(j2);
    }
  }
  __syncthreads();

  // cross-wave merge + finalize (one lane per row)
  if (t < 16) {
    const int row = t, n = n0 + row;
    float Zf = 0.f, hvf = -INFINITY; int hif = 0;
    float v1 = -INFINITY, v2 = -INFINITY; int j1 = 0, j2 = 0;
    for (int w = 0; w < 4; ++w) {  // ascending m order -> ties keep first
      const float* rp = red[row][w];
      Zf += rp[0];
      float ohv = rp[1]; int ohi = __float_as_int(rp[2]);
      if (ohv > hvf || (ohv == hvf && ohi < hif)) { hvf = ohv; hif = ohi; }
      float w1 = rp[3], w2 = rp[5];
      int k1 = __float_as_int(rp[4]), k2 = __float_as_int(rp[6]);
      if (w1 > v1 || (w1 == v1 && k1 < j1)) {
        if (v1 > w2 || (v1 == w2 && j1 < k2)) { v2 = v1; j2 = j1; }
        else { v2 = w2; j2 = k2; }
        v1 = w1; j1 = k1;
      } else if (w1 > v2 || (w1 == v2 && k1 < j2)) { v2 = w1; j2 = k1; }
    }
    int fidx = j1;
    if (v1 - v2 < REFINE_GAP) {
      // exact fp64 re-check of the two candidates (rare: ~1% of rows)
      const float* xrow = x + (size_t)n * (GG * DD) + (size_t)g * DD;
      const float* eA = emb + ((size_t)g * MM + j1) * DD;
      const float* eB = emb + ((size_t)g * MM + j2) * DD;
      double dA = 0, sA = 0, dB = 0, sB = 0;
      for (int d = 0; d < DD; ++d) {
        double xv = xrow[d], ea = eA[d], eb = eB[d];
        dA += xv * ea; sA += ea * ea;
        dB += xv * eb; sB += eb * eb;
      }
      double uA = gum[((size_t)n * GG + g) * MM + j1];
      double uB = gum[((size_t)n * GG + g) * MM + j2];
      double zA = 2.0 * dA - sA - log(-log(uA));
      double zB = 2.0 * dB - sB - log(-log(uB));
      if (zB > zA || (zB == zA && j2 < j1)) fidx = j2;
    }
    out[OFF_I + (size_t)n * GG + g] = (float)fidx;
    atomicAdd(&hist[g * MM + hif], 1);
    fin_invZ[row] = 1.f / Zf;
    fin_idx[row] = fidx;
  }
  __syncthreads();

  // quantized rows + commitment-loss partial (emb/x re-reads hit L1/L2)
  {
    const int row = t >> 4, c = (t & 15) * 16;
    const int n = n0 + row, fidx = fin_idx[row];
    const float* er = emb + ((size_t)g * MM + fidx) * DD + c;
    const float* xq = x + (size_t)n * (GG * DD) + (size_t)g * DD + c;
    float* op = out + OFF_Q + (size_t)n * (GG * DD) + (size_t)g * DD + c;
    float ls = 0.f;
#pragma unroll
    for (int j = 0; j < 4; ++j) {
      float4 e4 = *(const float4*)(er + j * 4);
      float4 x4 = *(const float4*)(xq + j * 4);
      *(float4*)(op + j * 4) = e4;
      float dx = x4.x - e4.x, dy = x4.y - e4.y, dz = x4.z - e4.z, dw = x4.w - e4.w;
      ls += dx * dx + dy * dy + dz * dz + dw * dw;
    }
    ls = wave_sum_f(ls);
    if (lane == 0) atomicAdd(loss, (double)ls);
  }

  // avg_probs: scale stored exps by invZ, reduce quads, accumulate per-col
  float iZ[4];
#pragma unroll
  for (int r = 0; r < 4; ++r) iZ[r] = fin_invZ[quad * 4 + r];
#pragma unroll 1
  for (int tt = 0; tt < 16; ++tt) {
    float v = 0.f;
#pragma unroll
    for (int r = 0; r < 4; ++r)
      v += bf2f(est_lds[wave][quad * 4 + r][tt * 16 + l15]) * iZ[r];
    v += __shfl_xor(v, 16);
    v += __shfl_xor(v, 32);
    if (lane < 16) colsum[wm0 + tt * 16 + lane] += v;  // wave-exclusive cols
  }
  __syncthreads();
  for (int i = t; i < MM; i += 256) atomicAdd(&avg[g * MM + i], colsum[i]);
}

// ---- round-1 fallback main (used only if ws_size too small for eh/el) ----
#define BLOCK_ROWS 16
#define RPW 2
#define NTHREADS 512
#define DCH 32
#define EPITCH 260

__device__ inline double wave_sum_d(double v) {
#pragma unroll
  for (int o = 32; o > 0; o >>= 1) v += __shfl_xor(v, o);
  return v;
}

__global__ __launch_bounds__(NTHREADS) void vq_main_r1(
    const float* __restrict__ x, const float* __restrict__ emb,
    const float* __restrict__ gum, const float* __restrict__ sq_e,
    float* __restrict__ out, float* __restrict__ avg,
    int* __restrict__ hist, double* __restrict__ loss) {
  __shared__ float e_t[DCH][EPITCH];
  __shared__ float x_t[BLOCK_ROWS][DD];
  __shared__ float colsum[MM];
  __shared__ float sqe_s[MM];

  const int g = blockIdx.y;
  const int n0 = blockIdx.x * BLOCK_ROWS;
  const int t = threadIdx.x;
  const int wave = t >> 6, lane = t & 63;
  const float* eg = emb + (size_t)g * MM * DD;

#pragma unroll
  for (int p = 0; p < 2; ++p) {
    int idx = p * NTHREADS + t;
    int row = idx >> 6, f4 = idx & 63;
    *(float4*)&x_t[row][f4 * 4] =
        *(const float4*)&x[(size_t)(n0 + row) * (GG * DD) + (size_t)g * DD + f4 * 4];
  }
  for (int i = t; i < MM; i += NTHREADS) {
    colsum[i] = 0.f;
    sqe_s[i] = sq_e[g * MM + i];
  }

  float Z[RPW] = {0.f, 0.f};
  float hval[RPW] = {-INFINITY, -INFINITY};
  int hidx[RPW] = {0, 0};
  float z1[RPW] = {-INFINITY, -INFINITY}, z2[RPW] = {-INFINITY, -INFINITY};
  int zi1[RPW] = {0, 0}, zi2[RPW] = {0, 0};
  float estore[RPW][16];

#pragma unroll
  for (int mg = 0; mg < 4; ++mg) {
    float acc[RPW][4] = {{0.f, 0.f, 0.f, 0.f}, {0.f, 0.f, 0.f, 0.f}};
#pragma unroll 1
    for (int dc = 0; dc < DD / DCH; ++dc) {
      __syncthreads();
#pragma unroll
      for (int p = 0; p < 4; ++p) {
        int idx = p * NTHREADS + t;
        int ml = idx >> 3, d4 = (idx & 7) * 4;
        float4 v = *(const float4*)&eg[(size_t)(mg * 256 + ml) * DD + dc * DCH + d4];
        e_t[d4 + 0][ml] = v.x;
        e_t[d4 + 1][ml] = v.y;
        e_t[d4 + 2][ml] = v.z;
        e_t[d4 + 3][ml] = v.w;
      }
      __syncthreads();
#pragma unroll
      for (int d = 0; d < DCH; ++d) {
        float4 e4 = *(const float4*)&e_t[d][lane * 4];
#pragma unroll
        for (int r = 0; r < RPW; ++r) {
          float xv = x_t[wave * RPW + r][dc * DCH + d];
          acc[r][0] = fmaf(xv, e4.x, acc[r][0]);
          acc[r][1] = fmaf(xv, e4.y, acc[r][1]);
          acc[r][2] = fmaf(xv, e4.z, acc[r][2]);
          acc[r][3] = fmaf(xv, e4.w, acc[r][3]);
        }
      }
    }
    float4 sq4 = *(const float4*)&sqe_s[mg * 256 + lane * 4];
    const float sqv[4] = {sq4.x, sq4.y, sq4.z, sq4.w};
#pragma unroll
    for (int r = 0; r < RPW; ++r) {
      int n = n0 + wave * RPW + r;
      float4 u4 = *(const float4*)&gum[(size_t)n * (GG * MM) + (size_t)g * MM + mg * 256 + lane * 4];
      const float uu[4] = {u4.x, u4.y, u4.z, u4.w};
#pragma unroll
      for (int q = 0; q < 4; ++q) {
        int m = mg * 256 + lane * 4 + q;
        float lp = 2.f * acc[r][q] - sqv[q];
        float ev = expf(lp);
        Z[r] += ev;
        estore[r][mg * 4 + q] = ev;
        if (lp > hval[r]) { hval[r] = lp; hidx[r] = m; }
        float gmb = -logf(-logf(uu[q]));
        float z = lp + gmb;
        if (z > z1[r]) { z2[r] = z1[r]; zi2[r] = zi1[r]; z1[r] = z; zi1[r] = m; }
        else if (z > z2[r]) { z2[r] = z; zi2[r] = m; }
      }
    }
  }

#pragma unroll
  for (int r = 0; r < RPW; ++r) {
    const int row = wave * RPW + r;
    const int n = n0 + row;
    float Zr = wave_sum_f(Z[r]);
    float hv = hval[r]; int hi = hidx[r];
#pragma unroll
    for (int o = 32; o > 0; o >>= 1) {
      float ov = __shfl_xor(hv, o); int oi = __shfl_xor(hi, o);
      if (ov > hv || (ov == hv && oi < hi)) { hv = ov; hi = oi; }
    }
    float v1 = z1[r], v2 = z2[r]; int i1 = zi1[r], i2 = zi2[r];
#pragma unroll
    for (int o = 32; o > 0; o >>= 1) {
      float w1 = __shfl_xor(v1, o), w2 = __shfl_xor(v2, o);
      int j1 = __shfl_xor(i1, o), j2 = __shfl_xor(i2, o);
      if (w1 > v1 || (w1 == v1 && j1 < i1)) {
        float nv2; int ni2;
        if (v1 > w2 || (v1 == w2 && i1 < j2)) { nv2 = v1; ni2 = i1; }
        else { nv2 = w2; ni2 = j2; }
        v1 = w1; i1 = j1; v2 = nv2; i2 = ni2;
      } else if (w1 > v2 || (w1 == v2 && j1 < i2)) {
        v2 = w1; i2 = j1;
      }
    }
    int fidx = i1;
    if (v1 - v2 < 1e-2f) {
      const float* erA = eg + (size_t)i1 * DD;
      const float* erB = eg + (size_t)i2 * DD;
      double dA = 0, sA = 0, dB = 0, sB = 0;
#pragma unroll
      for (int k = 0; k < 4; ++k) {
        int d = lane * 4 + k;
        double xv = (double)x_t[row][d];
        double ea = (double)erA[d], eb = (double)erB[d];
        dA += xv * ea; sA += ea * ea;
        dB += xv * eb; sB += eb * eb;
      }
      dA = wave_sum_d(dA); sA = wave_sum_d(sA);
      dB = wave_sum_d(dB); sB = wave_sum_d(sB);
      double uA = (double)gum[(size_t)n * (GG * MM) + (size_t)g * MM + i1];
      double uB = (double)gum[(size_t)n * (GG * MM) + (size_t)g * MM + i2];
      double zA = 2.0 * dA - sA - log(-log(uA));
      double zB = 2.0 * dB - sB - log(-log(uB));
      if (zB > zA || (zB == zA && i2 < i1)) fidx = i2;
    }
    if (lane == 0) {
      out[OFF_I + (size_t)n * GG + g] = (float)fidx;
      atomicAdd(&hist[g * MM + hi], 1);
    }
    const float* er = eg + (size_t)fidx * DD;
    float4 ev4 = *(const float4*)&er[lane * 4];
    float4 xv4 = *(const float4*)&x_t[row][lane * 4];
    *(float4*)&out[OFF_Q + (size_t)n * (GG * DD) + (size_t)g * DD + lane * 4] = ev4;
    float dx = xv4.x - ev4.x, dy = xv4.y - ev4.y, dz = xv4.z - ev4.z, dw = xv4.w - ev4.w;
    float ds = wave_sum_f(dx * dx + dy * dy + dz * dz + dw * dw);
    if (lane == 0) atomicAdd(loss, (double)ds);
    float invZ = 1.f / Zr;
#pragma unroll
    for (int mg = 0; mg < 4; ++mg)
#pragma unroll
      for (int q = 0; q < 4; ++q)
        atomicAdd(&colsum[mg * 256 + lane * 4 + q], estore[r][mg * 4 + q] * invZ);
  }
  __syncthreads();
  for (int i = t; i < MM; i += NTHREADS)
    atomicAdd(&avg[g * MM + i], colsum[i]);
}

// ---- finalize: entropies + loss ----
__global__ void vq_fin(const float* __restrict__ avg, const int* __restrict__ hist,
                       const double* __restrict__ loss, float* __restrict__ out) {
  int g = blockIdx.x, t = threadIdx.x;
  float cp = 0.f, pp = 0.f;
  for (int m = t; m < MM; m += 256) {
    float hp = (float)hist[g * MM + m] * (1.f / 16384.f);
    cp += hp * log2f(hp + 1e-10f);
    float ap = avg[g * MM + m] * (1.f / 16384.f);
    pp += ap * log2f(ap + 1e-10f);
  }
  cp = wave_sum_f(cp);
  pp = wave_sum_f(pp);
  __shared__ float sc[4], sp[4];
  int wave = t >> 6, lane = t & 63;
  if (lane == 0) { sc[wave] = cp; sp[wave] = pp; }
  __syncthreads();
  if (t == 0) {
    out[OFF_CP + g] = -(sc[0] + sc[1] + sc[2] + sc[3]);
    out[OFF_PP + g] = -(sp[0] + sp[1] + sp[2] + sp[3]);
    if (g == 0) out[OFF_L] = (float)(*loss * (1.0 / 8388608.0));
  }
}

extern "C" void kernel_launch(void* const* d_in, const int* in_sizes, int n_in,
                              void* d_out, int out_size, void* d_ws, size_t ws_size,
                              hipStream_t stream) {
  const float* x = (const float*)d_in[0];
  const float* emb = (const float*)d_in[1];
  const float* gum = (const float*)d_in[2];
  float* out = (float*)d_out;
  // ws layout: sq_e f32[2048] | avg f32[2048] | hist i32[2048] | loss f64 |
  //            (pad to 32768) eh bf16[2*1024*256] | el bf16[2*1024*256]
  float* sq_e = (float*)d_ws;
  float* avg = sq_e + 2048;
  int* hist = (int*)(avg + 2048);
  double* loss = (double*)((char*)d_ws + 24576);
  unsigned short* eh = (unsigned short*)((char*)d_ws + 32768);
  unsigned short* el = eh + (size_t)GG * MM * DD;
  const size_t WS_NEED = 32768 + 2 * (size_t)GG * MM * DD * sizeof(unsigned short);
  const int fast = (ws_size >= WS_NEED) ? 1 : 0;

  vq_init2<<<512, 256, 0, stream>>>(emb, sq_e, avg, hist, loss, eh, el, fast);
  if (fast) {
    vq_main_fast<<<dim3(NTOT / 16, GG), 256, 0, stream>>>(
        x, emb, gum, sq_e, eh, el, out, avg, hist, loss);
  } else {
    vq_main_r1<<<dim3(NTOT / BLOCK_ROWS, GG), NTHREADS, 0, stream>>>(
        x, emb, gum, sq_e, out, avg, hist, loss);
  }
  vq_fin<<<GG, 256, 0, stream>>>(avg, hist, loss, out);
}

// Round 3
// 401.000 us; speedup vs baseline: 2.5447x; 1.3244x over previous
//
#include <hip/hip_runtime.h>
#include <math.h>

// Problem constants
#define NTOT 16384        // N = B*T
#define GG 2
#define MM 1024
#define DD 256

// Output layout (flat float32)
#define OFF_Q  ((size_t)0)
#define OFF_CP ((size_t)8388608)
#define OFF_PP ((size_t)8388610)
#define OFF_I  ((size_t)8388612)
#define OFF_L  ((size_t)8421380)

#define SHIFT 40.0f       // row-constant logit shift (softmax/argmax invariant)
#define REFINE_GAP 0.03f  // fp64 re-check threshold (split-bf16 z err << this)

typedef __attribute__((ext_vector_type(8))) short bf16x8;
typedef __attribute__((ext_vector_type(4))) float f32x4;
typedef unsigned short u16;
typedef unsigned int u32;

__device__ inline float wave_sum_f(float v) {
#pragma unroll
  for (int o = 32; o > 0; o >>= 1) v += __shfl_xor(v, o);
  return v;
}
__device__ inline u16 f2bf(float f) {
  u32 u = __float_as_uint(f);
  return (u16)((u + 0x7fffu + ((u >> 16) & 1u)) >> 16);
}
__device__ inline float bf2f(u16 h) {
  return __uint_as_float(((u32)h) << 16);
}
// async 16B global->LDS (LDS dest = wave-uniform base + lane*16)
__device__ inline void async16(const void* g, void* l) {
  __builtin_amdgcn_global_load_lds(
      (const __attribute__((address_space(1))) u32*)g,
      (__attribute__((address_space(3))) u32*)l, 16, 0, 0);
}

// ============ ws layout (v3) ============
// 0       sq_e f32[2048]
// 8192    avg  f32[2048]
// 16384   hist i32[2048]
// 24576   loss double
// 32768   invZ f32[2*16384]          (128KB)
// 163840  eh_sw u16[2*1024*256]      (1MB, MFMA-frag swizzled)
// 1212416 el_sw u16[2*1024*256]      (1MB)
// 2260992 est  u16[2*1024*16384]     (67MB, [g][m][n] bf16)
#define WS_INVZ   32768
#define WS_EHSW   163840
#define WS_ELSW   1212416
#define WS_EST    2260992
#define WS_NEED3  (2260992ull + 2ull * MM * (size_t)NTOT * GG)

// ---- init A: sq_e + zero hist/loss (+ optional row-major hi/lo for fallback)
__global__ void vq_init2(const float* __restrict__ emb, float* __restrict__ sq_e,
                         float* __restrict__ avg, int* __restrict__ hist,
                         double* __restrict__ loss, u16* __restrict__ eh,
                         u16* __restrict__ el, int do_split) {
  const int row = blockIdx.x * 4 + (threadIdx.x >> 6);
  const int lane = threadIdx.x & 63;
  float4 e4 = *(const float4*)&emb[(size_t)row * DD + lane * 4];
  float s = e4.x * e4.x + e4.y * e4.y + e4.z * e4.z + e4.w * e4.w;
  s = wave_sum_f(s);
  if (do_split) {
    ushort4 h, l;
    h.x = f2bf(e4.x); l.x = f2bf(e4.x - bf2f(h.x));
    h.y = f2bf(e4.y); l.y = f2bf(e4.y - bf2f(h.y));
    h.z = f2bf(e4.z); l.z = f2bf(e4.z - bf2f(h.z));
    h.w = f2bf(e4.w); l.w = f2bf(e4.w - bf2f(h.w));
    *(ushort4*)&eh[(size_t)row * DD + lane * 4] = h;
    *(ushort4*)&el[(size_t)row * DD + lane * 4] = l;
  }
  if (lane == 0) sq_e[row] = s;
  if (blockIdx.x == 0) {
    for (int i = threadIdx.x; i < GG * MM; i += 256) { avg[i] = 0.f; hist[i] = 0; }
    if (threadIdx.x == 0) *loss = 0.0;
  }
}

// ---- init B: build swizzled hi/lo tables in MFMA-frag chunk order.
// chunk(g,ct,ks,cg,quad,l15) = B[col=ct*64+cg*16+l15][k=ks*32+quad*8 .. +8]
// linear chunk idx = (((g*16+ct)*8+ks)*4+cg)*64 + quad*16 + l15, 16B each.
__global__ void vq_init_swz(const float* __restrict__ emb, u16* __restrict__ eh_sw,
                            u16* __restrict__ el_sw) {
  int tid = blockIdx.x * 256 + threadIdx.x;   // 0..65535
  int g = tid >> 15, rem = tid & 32767;
  int col = rem >> 5, kc = rem & 31;          // kc: 8-element k-chunk
  const float* src = emb + ((size_t)(g * MM + col)) * DD + kc * 8;
  float4 fa = *(const float4*)src;
  float4 fb = *(const float4*)(src + 4);
  float f[8] = {fa.x, fa.y, fa.z, fa.w, fb.x, fb.y, fb.z, fb.w};
  u16 hi[8], lo[8];
#pragma unroll
  for (int j = 0; j < 8; ++j) {
    hi[j] = f2bf(f[j]);
    lo[j] = f2bf(f[j] - bf2f(hi[j]));
  }
  int ct = col >> 6, cg = (col >> 4) & 3, l15 = col & 15;
  int ks = kc >> 2, quad = kc & 3;
  size_t chunk = ((((size_t)g * 16 + ct) * 8 + ks) * 4 + cg) * 64 + quad * 16 + l15;
  ushort4* dh = (ushort4*)(eh_sw + chunk * 8);
  ushort4* dl = (ushort4*)(el_sw + chunk * 8);
  dh[0] = make_ushort4(hi[0], hi[1], hi[2], hi[3]);
  dh[1] = make_ushort4(hi[4], hi[5], hi[6], hi[7]);
  dl[0] = make_ushort4(lo[0], lo[1], lo[2], lo[3]);
  dl[1] = make_ushort4(lo[4], lo[5], lo[6], lo[7]);
}

// ---- main v3: 128 rows/block, row-split waves (32 rows = 2 strips each),
// B double-buffered through LDS via global_load_lds, est -> ws (bf16).
__global__ __launch_bounds__(256, 2) void vq_main3(
    const float* __restrict__ x, const float* __restrict__ emb,
    const float* __restrict__ gum, const float* __restrict__ sq_e,
    const u16* __restrict__ eh_sw, const u16* __restrict__ el_sw,
    float* __restrict__ out, u16* __restrict__ est, float* __restrict__ invZ_ws,
    int* __restrict__ hist, double* __restrict__ loss) {
  __shared__ u16 bt[2][32768];     // 2 x 64KB B tile buffers (also x-stage at start)
  __shared__ int fidx_lds[128];

  const int g = blockIdx.y;
  const int n0 = blockIdx.x * 128;
  const int t = threadIdx.x;
  const int wave = t >> 6, lane = t & 63;
  const int quad = lane >> 4, l15 = lane & 15;
  const int nw = n0 + wave * 32;   // this wave's first row

  // ---- stage this wave's 32 x-rows into LDS (xor-swizzled, conflict-free) ----
  float* xs = (float*)&bt[0][0];   // 32768 floats = 128KB, wave region = 8192
  {
    const float* xb = x + (size_t)nw * (GG * DD) + (size_t)g * DD;
#pragma unroll 4
    for (int j = 0; j < 32; ++j) {
      float4 v = *(const float4*)(xb + (size_t)j * (GG * DD) + lane * 4);
      *(float4*)&xs[wave * 8192 + j * 256 + ((lane ^ (j & 7)) << 2)] = v;
    }
  }
  __syncthreads();

  // ---- build A fragments (2 strips x 8 k-steps, hi+lo split-bf16) ----
  bf16x8 ah[2][8], al[2][8];
#pragma unroll
  for (int s = 0; s < 2; ++s) {
#pragma unroll
    for (int ks = 0; ks < 8; ++ks) {
      int row = s * 16 + l15;
      int c0 = ks * 8 + quad * 2;
      const float* base = &xs[wave * 8192 + row * 256];
      float4 f0 = *(const float4*)&base[((c0 ^ (row & 7)) << 2)];
      float4 f1 = *(const float4*)&base[(((c0 + 1) ^ (row & 7)) << 2)];
      float f[8] = {f0.x, f0.y, f0.z, f0.w, f1.x, f1.y, f1.z, f1.w};
#pragma unroll
      for (int j = 0; j < 8; ++j) {
        u16 h = f2bf(f[j]);
        ah[s][ks][j] = (short)h;
        al[s][ks][j] = (short)f2bf(f[j] - bf2f(h));
      }
    }
  }
  __syncthreads();   // xs fully consumed; bt now reusable for B tiles

  const u16* sgh = eh_sw + (size_t)g * 16 * 16384;  // 16 tiles x 32KB
  const u16* sgl = el_sw + (size_t)g * 16 * 16384;

  auto stage = [&](int ct, int buf) {
    const u16* sh = sgh + (size_t)ct * 16384;
    const u16* sl = sgl + (size_t)ct * 16384;
    u16* dh = &bt[buf][0];
    u16* dl = &bt[buf][16384];
#pragma unroll
    for (int j = 0; j < 8; ++j) {
      int slot = j * 4 + wave;   // 32 slots x 1KB per table
      async16(sh + slot * 512 + lane * 8, dh + slot * 512);
      async16(sl + slot * 512 + lane * 8, dl + slot * 512);
    }
  };

  // per-lane per-row state (8 rows: s in {0,1}, r in 0..3; row = s*16+quad*4+r)
  float Zl[8], hv[8], z1[8], z2[8];
  int hid[8], i1[8], i2[8];
#pragma unroll
  for (int i = 0; i < 8; ++i) {
    Zl[i] = 0.f; hv[i] = -INFINITY; z1[i] = -INFINITY; z2[i] = -INFINITY;
    hid[i] = 0; i1[i] = 0; i2[i] = 0;
  }

  stage(0, 0);

#pragma unroll 1
  for (int ct = 0; ct < 16; ++ct) {
    __syncthreads();                     // stage(ct) landed; prev tile reads done
    if (ct < 15) stage(ct + 1, (ct + 1) & 1);
    const u16* bh_p = &bt[ct & 1][0];
    const u16* bl_p = &bt[ct & 1][16384];
#pragma unroll 1
    for (int cg = 0; cg < 4; ++cg) {
      const int colG = ct * 64 + cg * 16 + l15;
      float sqv = sq_e[g * MM + colG];
      float gv[8];
#pragma unroll
      for (int s = 0; s < 2; ++s)
#pragma unroll
        for (int r = 0; r < 4; ++r)
          gv[s * 4 + r] =
              gum[((size_t)(nw + s * 16 + quad * 4 + r) * GG + g) * MM + colG];

      f32x4 c00 = {0,0,0,0}, c01 = {0,0,0,0}, c02 = {0,0,0,0};
      f32x4 c10 = {0,0,0,0}, c11 = {0,0,0,0}, c12 = {0,0,0,0};
#pragma unroll
      for (int ks = 0; ks < 8; ++ks) {
        int off = ((ks * 4 + cg) * 64 + lane) * 8;
        bf16x8 bh = *(const bf16x8*)(bh_p + off);
        bf16x8 bl = *(const bf16x8*)(bl_p + off);
        c00 = __builtin_amdgcn_mfma_f32_16x16x32_bf16(ah[0][ks], bh, c00, 0, 0, 0);
        c01 = __builtin_amdgcn_mfma_f32_16x16x32_bf16(ah[0][ks], bl, c01, 0, 0, 0);
        c02 = __builtin_amdgcn_mfma_f32_16x16x32_bf16(al[0][ks], bh, c02, 0, 0, 0);
        c10 = __builtin_amdgcn_mfma_f32_16x16x32_bf16(ah[1][ks], bh, c10, 0, 0, 0);
        c11 = __builtin_amdgcn_mfma_f32_16x16x32_bf16(ah[1][ks], bl, c11, 0, 0, 0);
        c12 = __builtin_amdgcn_mfma_f32_16x16x32_bf16(al[1][ks], bh, c12, 0, 0, 0);
      }
#pragma unroll
      for (int s = 0; s < 2; ++s) {
        const f32x4& a0 = s ? c10 : c00;
        const f32x4& a1 = s ? c11 : c01;
        const f32x4& a2 = s ? c12 : c02;
        ushort4 pk;
        u16* pp = (u16*)&pk;
#pragma unroll
        for (int r = 0; r < 4; ++r) {
          float lp = 2.f * (a0[r] + a1[r] + a2[r]) - sqv + SHIFT;
          float ev = expf(fminf(lp, 80.f));
          Zl[s * 4 + r] += ev;
          pp[r] = f2bf(ev);
          if (lp > hv[s * 4 + r]) { hv[s * 4 + r] = lp; hid[s * 4 + r] = colG; }
          float zz = lp - logf(-logf(gv[s * 4 + r]));
          if (zz > z1[s * 4 + r]) {
            z2[s * 4 + r] = z1[s * 4 + r]; i2[s * 4 + r] = i1[s * 4 + r];
            z1[s * 4 + r] = zz; i1[s * 4 + r] = colG;
          } else if (zz > z2[s * 4 + r]) {
            z2[s * 4 + r] = zz; i2[s * 4 + r] = colG;
          }
        }
        // est[g][m][n] bf16, 4 consecutive n per lane
        *(ushort4*)&est[((size_t)(g * MM + colG) << 14) + nw + s * 16 + quad * 4] = pk;
      }
    }
  }

  // ---- per-row finalize: reduce over the 16 l15 lanes of each quad ----
#pragma unroll 1
  for (int s = 0; s < 2; ++s) {
#pragma unroll 1
    for (int r = 0; r < 4; ++r) {
      const int idx = s * 4 + r;
      const int row = wave * 32 + s * 16 + quad * 4 + r;
      const int n = n0 + row;
      float Zr = Zl[idx], hvr = hv[idx];
      int hir = hid[idx];
      float v1 = z1[idx], v2 = z2[idx];
      int j1 = i1[idx], j2 = i2[idx];
#pragma unroll
      for (int o = 1; o <= 8; o <<= 1) {
        Zr += __shfl_xor(Zr, o);
        float ohv = __shfl_xor(hvr, o); int ohi = __shfl_xor(hir, o);
        if (ohv > hvr || (ohv == hvr && ohi < hir)) { hvr = ohv; hir = ohi; }
        float w1 = __shfl_xor(v1, o), w2 = __shfl_xor(v2, o);
        int k1 = __shfl_xor(j1, o), k2 = __shfl_xor(j2, o);
        if (w1 > v1 || (w1 == v1 && k1 < j1)) {
          if (v1 > w2 || (v1 == w2 && j1 < k2)) { v2 = v1; j2 = j1; }
          else { v2 = w2; j2 = k2; }
          v1 = w1; j1 = k1;
        } else if (w1 > v2 || (w1 == v2 && k1 < j2)) { v2 = w1; j2 = k1; }
      }
      int fidx = j1;
      if (v1 - v2 < REFINE_GAP) {
        // exact fp64 re-check, 16-lane parallel over d
        const float* xrow = x + (size_t)n * (GG * DD) + (size_t)g * DD;
        const float* eA = emb + ((size_t)g * MM + j1) * DD;
        const float* eB = emb + ((size_t)g * MM + j2) * DD;
        double dA = 0, sA = 0, dB = 0, sB = 0;
#pragma unroll
        for (int k = 0; k < 16; ++k) {
          int d = l15 * 16 + k;
          double xv = (double)xrow[d];
          double ea = (double)eA[d], eb = (double)eB[d];
          dA += xv * ea; sA += ea * ea;
          dB += xv * eb; sB += eb * eb;
        }
#pragma unroll
        for (int o = 1; o <= 8; o <<= 1) {
          dA += __shfl_xor(dA, o); sA += __shfl_xor(sA, o);
          dB += __shfl_xor(dB, o); sB += __shfl_xor(sB, o);
        }
        double uA = (double)gum[((size_t)n * GG + g) * MM + j1];
        double uB = (double)gum[((size_t)n * GG + g) * MM + j2];
        double zA = 2.0 * dA - sA - log(-log(uA));
        double zB = 2.0 * dB - sB - log(-log(uB));
        if (zB > zA || (zB == zA && j2 < j1)) fidx = j2;
      }
      if (l15 == 0) {
        out[OFF_I + (size_t)n * GG + g] = (float)fidx;
        atomicAdd(&hist[g * MM + hir], 1);
        invZ_ws[g * NTOT + n] = 1.f / Zr;
        fidx_lds[row] = fidx;
      }
    }
  }
  __syncthreads();

  // ---- quantized rows + commitment-loss partial (coalesced) ----
  {
    float ls = 0.f;
#pragma unroll 4
    for (int j = 0; j < 32; ++j) {
      int idx = j * 256 + t;
      int row = idx >> 6, f4 = idx & 63;
      int n = n0 + row, fi = fidx_lds[row];
      float4 e4 = *(const float4*)&emb[((size_t)g * MM + fi) * DD + f4 * 4];
      float4 x4 = *(const float4*)&x[(size_t)n * (GG * DD) + (size_t)g * DD + f4 * 4];
      *(float4*)&out[OFF_Q + (size_t)n * (GG * DD) + (size_t)g * DD + f4 * 4] = e4;
      float dx = x4.x - e4.x, dy = x4.y - e4.y, dz = x4.z - e4.z, dw = x4.w - e4.w;
      ls += dx * dx + dy * dy + dz * dz + dw * dw;
    }
    ls = wave_sum_f(ls);
    if (lane == 0) atomicAdd(loss, (double)ls);
  }
}

// ---- avg_probs column reduction: avg[g][m] = sum_n est[g][m][n] * invZ[g][n]
__global__ void vq_avg(const u16* __restrict__ est, const float* __restrict__ invZ,
                       float* __restrict__ avg) {
  int wid = blockIdx.x * 4 + (threadIdx.x >> 6);   // 0..2047 = g*1024+m
  int lane = threadIdx.x & 63;
  const u16* base = est + ((size_t)wid << 14);
  const float* zp = invZ + ((wid >> 10) << 14);
  float acc = 0.f;
#pragma unroll 4
  for (int it = 0; it < 64; ++it) {
    int n = it * 256 + lane * 4;
    ushort4 e4 = *(const ushort4*)(base + n);
    float4 z4 = *(const float4*)(zp + n);
    acc += bf2f(e4.x) * z4.x + bf2f(e4.y) * z4.y +
           bf2f(e4.z) * z4.z + bf2f(e4.w) * z4.w;
  }
  acc = wave_sum_f(acc);
  if (lane == 0) avg[wid] = acc;
}

// ---- finalize: entropies + loss ----
__global__ void vq_fin(const float* __restrict__ avg, const int* __restrict__ hist,
                       const double* __restrict__ loss, float* __restrict__ out) {
  int g = blockIdx.x, t = threadIdx.x;
  float cp = 0.f, pp = 0.f;
  for (int m = t; m < MM; m += 256) {
    float hp = (float)hist[g * MM + m] * (1.f / 16384.f);
    cp += hp * log2f(hp + 1e-10f);
    float ap = avg[g * MM + m] * (1.f / 16384.f);
    pp += ap * log2f(ap + 1e-10f);
  }
  cp = wave_sum_f(cp);
  pp = wave_sum_f(pp);
  __shared__ float sc[4], sp[4];
  int wave = t >> 6, lane = t & 63;
  if (lane == 0) { sc[wave] = cp; sp[wave] = pp; }
  __syncthreads();
  if (t == 0) {
    out[OFF_CP + g] = -(sc[0] + sc[1] + sc[2] + sc[3]);
    out[OFF_PP + g] = -(sp[0] + sp[1] + sp[2] + sp[3]);
    if (g == 0) out[OFF_L] = (float)(*loss * (1.0 / 8388608.0));
  }
}

// ================= R2 fallback main (small ws) =================
__global__ __launch_bounds__(256, 3) void vq_main_fast(
    const float* __restrict__ x, const float* __restrict__ emb,
    const float* __restrict__ gum, const float* __restrict__ sq_e,
    const u16* __restrict__ eh, const u16* __restrict__ el,
    float* __restrict__ out, float* __restrict__ avg,
    int* __restrict__ hist, double* __restrict__ loss) {
  __shared__ u16 est_lds[4][16][264];
  __shared__ float colsum[MM];
  __shared__ float red[16][4][8];
  __shared__ float fin_invZ[16];
  __shared__ int fin_idx[16];

  const int g = blockIdx.y;
  const int n0 = blockIdx.x * 16;
  const int t = threadIdx.x;
  const int wave = t >> 6, lane = t & 63;
  const int quad = lane >> 4, l15 = lane & 15;
  const int wm0 = wave * 256;

  for (int i = t; i < MM; i += 256) colsum[i] = 0.f;

  bf16x8 ah[8], al[8];
  {
    const float* xr = x + (size_t)(n0 + l15) * (GG * DD) + (size_t)g * DD + quad * 8;
#pragma unroll
    for (int ks = 0; ks < 8; ++ks) {
      float4 fa = *(const float4*)(xr + ks * 32);
      float4 fb = *(const float4*)(xr + ks * 32 + 4);
      float f[8] = {fa.x, fa.y, fa.z, fa.w, fb.x, fb.y, fb.z, fb.w};
#pragma unroll
      for (int j = 0; j < 8; ++j) {
        u16 h = f2bf(f[j]);
        ah[ks][j] = (short)h;
        al[ks][j] = (short)f2bf(f[j] - bf2f(h));
      }
    }
  }
  const u16* ehb = eh + ((size_t)g * MM + wm0 + l15) * DD + quad * 8;
  const u16* elb = el + ((size_t)g * MM + wm0 + l15) * DD + quad * 8;
  const float* sqb = sq_e + g * MM + wm0 + l15;

  float Z[4] = {0.f, 0.f, 0.f, 0.f};
  float hv[4] = {-INFINITY, -INFINITY, -INFINITY, -INFINITY};
  int hid[4] = {0, 0, 0, 0};
  float z1[4] = {-INFINITY, -INFINITY, -INFINITY, -INFINITY};
  float z2[4] = {-INFINITY, -INFINITY, -INFINITY, -INFINITY};
  int i1[4] = {0, 0, 0, 0}, i2[4] = {0, 0, 0, 0};

#pragma unroll 2
  for (int tt = 0; tt < 16; ++tt) {
    float sqv = sqb[tt * 16];
    float gv[4];
#pragma unroll
    for (int r = 0; r < 4; ++r)
      gv[r] = gum[((size_t)(n0 + quad * 4 + r) * GG + g) * MM + wm0 + tt * 16 + l15];
    f32x4 a0 = {0,0,0,0}, a1 = {0,0,0,0}, a2 = {0,0,0,0};
#pragma unroll
    for (int ks = 0; ks < 8; ++ks) {
      bf16x8 bh = *(const bf16x8*)(ehb + (size_t)tt * 16 * DD + ks * 32);
      bf16x8 bl = *(const bf16x8*)(elb + (size_t)tt * 16 * DD + ks * 32);
      a0 = __builtin_amdgcn_mfma_f32_16x16x32_bf16(ah[ks], bh, a0, 0, 0, 0);
      a1 = __builtin_amdgcn_mfma_f32_16x16x32_bf16(ah[ks], bl, a1, 0, 0, 0);
      a2 = __builtin_amdgcn_mfma_f32_16x16x32_bf16(al[ks], bh, a2, 0, 0, 0);
    }
    const int colL = tt * 16 + l15;
    const int colG = wm0 + colL;
#pragma unroll
    for (int r = 0; r < 4; ++r) {
      float lp = 2.f * (a0[r] + a1[r] + a2[r]) - sqv + SHIFT;
      float ev = expf(fminf(lp, 80.f));
      Z[r] += ev;
      est_lds[wave][quad * 4 + r][colL] = f2bf(ev);
      if (lp > hv[r]) { hv[r] = lp; hid[r] = colG; }
      float zz = lp - logf(-logf(gv[r]));
      if (zz > z1[r]) { z2[r] = z1[r]; i2[r] = i1[r]; z1[r] = zz; i1[r] = colG; }
      else if (zz > z2[r]) { z2[r] = zz; i2[r] = colG; }
    }
  }
#pragma unroll
  for (int r = 0; r < 4; ++r) {
    float Zr = Z[r], hvr = hv[r];
    int hir = hid[r];
    float v1 = z1[r], v2 = z2[r];
    int j1 = i1[r], j2 = i2[r];
#pragma unroll
    for (int o = 1; o <= 8; o <<= 1) {
      Zr += __shfl_xor(Zr, o);
      float ohv = __shfl_xor(hvr, o); int ohi = __shfl_xor(hir, o);
      if (ohv > hvr || (ohv == hvr && ohi < hir)) { hvr = ohv; hir = ohi; }
      float w1 = __shfl_xor(v1, o), w2 = __shfl_xor(v2, o);
      int k1 = __shfl_xor(j1, o), k2 = __shfl_xor(j2, o);
      if (w1 > v1 || (w1 == v1 && k1 < j1)) {
        if (v1 > w2 || (v1 == w2 && j1 < k2)) { v2 = v1; j2 = j1; }
        else { v2 = w2; j2 = k2; }
        v1 = w1; j1 = k1;
      } else if (w1 > v2 || (w1 == v2 && k1 < j2)) { v2 = w1; j2 = k1; }
    }
    if (l15 == 0) {
      float* rp = red[quad * 4 + r][wave];
      rp[0] = Zr; rp[1] = hvr; rp[2] = __int_as_float(hir);
      rp[3] = v1; rp[4] = __int_as_float(j1);
      rp[5] = v2; rp[6] = __int_as_float(j2);
    }
  }
  __syncthreads();
  if (t < 16) {
    const int row = t, n = n0 + row;
    float Zf = 0.f, hvf = -INFINITY; int hif = 0;
    float v1 = -INFINITY, v2 = -INFINITY; int j1 = 0, j2 = 0;
    for (int w = 0; w < 4; ++w) {
      const float* rp = red[row][w];
      Zf += rp[0];
      float ohv = rp[1]; int ohi = __float_as_int(rp[2]);
      if (ohv > hvf || (ohv == hvf && ohi < hif)) { hvf = ohv; hif = ohi; }
      float w1 = rp[3], w2 = rp[5];
      int k1 = __float_as_int(rp[4]), k2 = __float_as_int(rp[6]);
      if (w1 > v1 || (w1 == v1 && k1 < j1)) {
        if (v1 > w2 || (v1 == w2 && j1 < k2)) { v2 = v1; j2 = j1; }
        else { v2 = w2; j2 = k2; }
        v1 = w1; j1 = k1;
      } else if (w1 > v2 || (w1 == v2 && k1 < j2)) { v2 = w1; j2 = k1; }
    }
    int fidx = j1;
    if (v1 - v2 < REFINE_GAP) {
      const float* xrow = x + (size_t)n * (GG * DD) + (size_t)g * DD;
      const float* eA = emb + ((size_t)g * MM + j1) * DD;
      const float* eB = emb + ((size_t)g * MM + j2) * DD;
      double dA = 0, sA = 0, dB = 0, sB = 0;
      for (int d = 0; d < DD; ++d) {
        double xv = xrow[d], ea = eA[d], eb = eB[d];
        dA += xv * ea; sA += ea * ea;
        dB += xv * eb; sB += eb * eb;
      }
      double uA = gum[((size_t)n * GG + g) * MM + j1];
      double uB = gum[((size_t)n * GG + g) * MM + j2];
      double zA = 2.0 * dA - sA - log(-log(uA));
      double zB = 2.0 * dB - sB - log(-log(uB));
      if (zB > zA || (zB == zA && j2 < j1)) fidx = j2;
    }
    out[OFF_I + (size_t)n * GG + g] = (float)fidx;
    atomicAdd(&hist[g * MM + hif], 1);
    fin_invZ[row] = 1.f / Zf;
    fin_idx[row] = fidx;
  }
  __syncthreads();
  {
    const int row = t >> 4, c = (t & 15) * 16;
    const int n = n0 + row, fidx = fin_idx[row];
    const float* er = emb + ((size_t)g * MM + fidx) * DD + c;
    const float* xq = x + (size_t)n * (GG * DD) + (size_t)g * DD + c;
    float* op = out + OFF_Q + (size_t)n * (GG * DD) + (size_t)g * DD + c;
    float ls = 0.f;
#pragma unroll
    for (int j = 0; j < 4; ++j) {
      float4 e4 = *(const float4*)(er + j * 4);
      float4 x4 = *(const float4*)(xq + j * 4);
      *(float4*)(op + j * 4) = e4;
      float dx = x4.x - e4.x, dy = x4.y - e4.y, dz = x4.z - e4.z, dw = x4.w - e4.w;
      ls += dx * dx + dy * dy + dz * dz + dw * dw;
    }
    ls = wave_sum_f(ls);
    if (lane == 0) atomicAdd(loss, (double)ls);
  }
  float iZ[4];
#pragma unroll
  for (int r = 0; r < 4; ++r) iZ[r] = fin_invZ[quad * 4 + r];
#pragma unroll 1
  for (int tt = 0; tt < 16; ++tt) {
    float v = 0.f;
#pragma unroll
    for (int r = 0; r < 4; ++r)
      v += bf2f(est_lds[wave][quad * 4 + r][tt * 16 + l15]) * iZ[r];
    v += __shfl_xor(v, 16);
    v += __shfl_xor(v, 32);
    if (lane < 16) colsum[wm0 + tt * 16 + lane] += v;
  }
  __syncthreads();
  for (int i = t; i < MM; i += 256) atomicAdd(&avg[g * MM + i], colsum[i]);
}

extern "C" void kernel_launch(void* const* d_in, const int* in_sizes, int n_in,
                              void* d_out, int out_size, void* d_ws, size_t ws_size,
                              hipStream_t stream) {
  const float* x = (const float*)d_in[0];
  const float* emb = (const float*)d_in[1];
  const float* gum = (const float*)d_in[2];
  float* out = (float*)d_out;

  float* sq_e = (float*)d_ws;
  float* avg = (float*)((char*)d_ws + 8192);
  int* hist = (int*)((char*)d_ws + 16384);
  double* loss = (double*)((char*)d_ws + 24576);

  if (ws_size >= WS_NEED3) {
    float* invZ = (float*)((char*)d_ws + WS_INVZ);
    u16* eh_sw = (u16*)((char*)d_ws + WS_EHSW);
    u16* el_sw = (u16*)((char*)d_ws + WS_ELSW);
    u16* est = (u16*)((char*)d_ws + WS_EST);
    vq_init2<<<512, 256, 0, stream>>>(emb, sq_e, avg, hist, loss, eh_sw, el_sw, 0);
    vq_init_swz<<<256, 256, 0, stream>>>(emb, eh_sw, el_sw);
    vq_main3<<<dim3(NTOT / 128, GG), 256, 0, stream>>>(
        x, emb, gum, sq_e, eh_sw, el_sw, out, est, invZ, hist, loss);
    vq_avg<<<512, 256, 0, stream>>>(est, invZ, avg);
    vq_fin<<<GG, 256, 0, stream>>>(avg, hist, loss, out);
  } else {
    // R2 fallback (needs 32KB + 2MB row-major hi/lo tables)
    u16* eh = (u16*)((char*)d_ws + 32768);
    u16* el = eh + (size_t)GG * MM * DD;
    vq_init2<<<512, 256, 0, stream>>>(emb, sq_e, avg, hist, loss, eh, el, 1);
    vq_main_fast<<<dim3(NTOT / 16, GG), 256, 0, stream>>>(
        x, emb, gum, sq_e, eh, el, out, avg, hist, loss);
    vq_fin<<<GG, 256, 0, stream>>>(avg, hist, loss, out);
  }
}